// Round 1
// baseline (33804.553 us; speedup 1.0000x reference)
//
#include <hip/hip_runtime.h>
#include <cstdint>
#include <cstddef>

// ---------------------------------------------------------------------------
// Binary AlexNet-1D (brevitas-style). Key identities:
//   bq(w)  = 0.1 * sign(w)          (sign(0) = +1)
//   bact(x)= sign(x)                (clamp is a no-op for the sign)
//   conv on +-1 activations = 0.1 * (integer sign-sum) + bias
//   maxpool commutes with the monotone map 0.1*k + b  -> pool integer sums
// So all binary layers are EXACT integer arithmetic + f64 affine epilogue.
// Layer 1 (real input) accumulates the +-x sum in f64, then affine+sign.
// ---------------------------------------------------------------------------

__global__ void sign_w_kernel(const float* __restrict__ w, int8_t* __restrict__ o, int n) {
    int i = blockIdx.x * blockDim.x + threadIdx.x;
    if (i < n) o[i] = (w[i] >= 0.0f) ? (int8_t)1 : (int8_t)-1;
}

// Layer 1: x[128][3][2560] * sign(w1)[256][3][23] (dil 7) -> maxpool(5, pad 2)
//          -> scale-bias -> sign -> out[128][256][482]
__global__ void conv1_kernel(const float* __restrict__ x,
                             const int8_t* __restrict__ wsg,
                             const float* __restrict__ b,
                             const float* __restrict__ sw,
                             const float* __restrict__ sb,
                             int8_t* __restrict__ out)
{
    const int Lout = 482, Cout = 256, Lconv = 2406, Lin = 2560;
    int idx = blockIdx.x * blockDim.x + threadIdx.x;
    int total = 128 * Cout * Lout;
    if (idx >= total) return;
    int lp = idx % Lout;
    int co = (idx / Lout) % Cout;
    int n  = idx / (Lout * Cout);

    const float* xb = x + (size_t)n * 3 * Lin;
    const int8_t* wp = wsg + co * 3 * 23;

    double best = -1e300;
    #pragma unroll
    for (int t = 0; t < 5; ++t) {
        int l = lp * 5 - 2 + t;
        if (l < 0 || l >= Lconv) continue;
        double s = 0.0;
        #pragma unroll
        for (int ci = 0; ci < 3; ++ci) {
            const float* xp = xb + ci * Lin + l;
            const int8_t* wq = wp + ci * 23;
            #pragma unroll
            for (int kk = 0; kk < 23; ++kk) {
                double xv = (double)xp[kk * 7];
                s += (wq[kk] > 0) ? xv : -xv;
            }
        }
        best = fmax(best, s);
    }
    // conv = 0.1*best + b ; v = (+-0.1)*conv + sb ; sign
    double conv = 0.1 * best + (double)b[co];
    double v = ((sw[co] >= 0.0f) ? 0.1 : -0.1) * conv + (double)sb[co];
    out[idx] = (v >= 0.0) ? (int8_t)1 : (int8_t)-1;
}

// Generic binary conv layer: act(+-1 int8) conv sign(w) (dilated) -> maxpool(PK, pad PP,
// stride PK) -> scale-bias -> sign.  PK==1, PP==0 means "no pool".
template<int CIN, int K, int DIL, int PK, int PP>
__global__ void bconv_kernel(const int8_t* __restrict__ act,  // [N][CIN][Lin]
                             const int8_t* __restrict__ wsg,  // [Cout][CIN][K]
                             const float* __restrict__ b,
                             const float* __restrict__ sw,
                             const float* __restrict__ sb,
                             int8_t* __restrict__ out,        // [N][Cout][Lout]
                             int Cout, int Lin, int Lconv, int Lout, int total)
{
    int idx = blockIdx.x * blockDim.x + threadIdx.x;
    if (idx >= total) return;
    int lp = idx % Lout;
    int co = (idx / Lout) % Cout;
    int n  = idx / (Lout * Cout);

    const int8_t* ab = act + (size_t)n * CIN * Lin;
    const int8_t* wp = wsg + (size_t)co * CIN * K;

    int best = -2147483647;
    #pragma unroll
    for (int t = 0; t < PK; ++t) {
        int l = lp * PK - PP + t;
        if (l < 0 || l >= Lconv) continue;
        int ksum = 0;
        for (int ci = 0; ci < CIN; ++ci) {
            const int8_t* ap = ab + ci * Lin + l;
            const int8_t* wq = wp + ci * K;
            #pragma unroll
            for (int kk = 0; kk < K; ++kk)
                ksum += (int)ap[kk * DIL] * (int)wq[kk];
        }
        best = (ksum > best) ? ksum : best;
    }
    double conv = 0.1 * (double)best + (double)b[co];
    double v = ((sw[co] >= 0.0f) ? 0.1 : -0.1) * conv + (double)sb[co];
    out[idx] = (v >= 0.0) ? (int8_t)1 : (int8_t)-1;
}

// FC1: a6[128][32] @ sign(fw1).T*0.1 -> *(+-0.1) + fsb1 -> sign -> h[128][512]
__global__ void fc1_kernel(const int8_t* __restrict__ a,
                           const int8_t* __restrict__ wsg,   // [512][32]
                           const float* __restrict__ fsw,
                           const float* __restrict__ fsb,
                           int8_t* __restrict__ h)
{
    int idx = blockIdx.x * blockDim.x + threadIdx.x;
    if (idx >= 128 * 512) return;
    int o = idx % 512;
    int n = idx / 512;
    int k = 0;
    #pragma unroll
    for (int i = 0; i < 32; ++i) k += (int)a[n * 32 + i] * (int)wsg[o * 32 + i];
    double pre = 0.1 * (double)k;
    double v = ((fsw[o] >= 0.0f) ? 0.1 : -0.1) * pre + (double)fsb[o];
    h[idx] = (v >= 0.0) ? (int8_t)1 : (int8_t)-1;
}

// FC2: h[128][512] @ sign(fw2).T*0.1 -> *(+-0.1) + fsb2 -> out f32 [128][1000]
__global__ void fc2_kernel(const int8_t* __restrict__ h,
                           const int8_t* __restrict__ wsg,   // [1000][512]
                           const float* __restrict__ fsw,
                           const float* __restrict__ fsb,
                           float* __restrict__ out)
{
    int idx = blockIdx.x * blockDim.x + threadIdx.x;
    if (idx >= 128 * 1000) return;
    int o = idx % 1000;
    int n = idx / 1000;
    int k = 0;
    for (int i = 0; i < 512; ++i) k += (int)h[n * 512 + i] * (int)wsg[o * 512 + i];
    double v = ((fsw[o] >= 0.0f) ? 0.1 : -0.1) * (0.1 * (double)k) + (double)fsb[o];
    out[idx] = (float)v;
}

extern "C" void kernel_launch(void* const* d_in, const int* in_sizes, int n_in,
                              void* d_out, int out_size, void* d_ws, size_t ws_size,
                              hipStream_t stream) {
    const float* x = (const float*)d_in[0];
    const float *w[6], *b[6], *sw[6], *sb[6];
    for (int i = 0; i < 6; ++i) {
        w[i]  = (const float*)d_in[1 + 4 * i];
        b[i]  = (const float*)d_in[2 + 4 * i];
        sw[i] = (const float*)d_in[3 + 4 * i];
        sb[i] = (const float*)d_in[4 + 4 * i];
    }
    const float* fw1  = (const float*)d_in[25];
    const float* fsw1 = (const float*)d_in[26];
    const float* fsb1 = (const float*)d_in[27];
    const float* fw2  = (const float*)d_in[28];
    const float* fsw2 = (const float*)d_in[29];
    const float* fsb2 = (const float*)d_in[30];
    float* out = (float*)d_out;

    // workspace carve-up (256B aligned)
    char* wsbase = (char*)d_ws;
    size_t off = 0;
    auto alloc = [&](size_t bytes) -> char* {
        char* p = wsbase + off;
        off = (off + bytes + 255) & ~(size_t)255;
        return p;
    };
    int8_t* w1s = (int8_t*)alloc(256 * 3 * 23);
    int8_t* w2s = (int8_t*)alloc(256 * 256 * 13);
    int8_t* w3s = (int8_t*)alloc(256 * 256 * 7);
    int8_t* w4s = (int8_t*)alloc(256 * 256 * 5);
    int8_t* w5s = (int8_t*)alloc(256 * 256 * 5);
    int8_t* w6s = (int8_t*)alloc(8 * 256 * 3);
    int8_t* f1s = (int8_t*)alloc(512 * 32);
    int8_t* f2s = (int8_t*)alloc(1000 * 512);
    int8_t* a1  = (int8_t*)alloc((size_t)128 * 256 * 482);
    int8_t* a2  = (int8_t*)alloc((size_t)128 * 256 * 149);
    int8_t* a3  = (int8_t*)alloc((size_t)128 * 256 * 46);
    int8_t* a4  = (int8_t*)alloc((size_t)128 * 256 * 42);
    int8_t* a5  = (int8_t*)alloc((size_t)128 * 256 * 13);
    int8_t* a6  = (int8_t*)alloc((size_t)128 * 32);
    int8_t* h1  = (int8_t*)alloc((size_t)128 * 512);
    (void)ws_size; (void)in_sizes; (void)n_in; (void)out_size;

    const int BLK = 256;
    auto gridOf = [](int n) { return dim3((unsigned)((n + 255) / 256)); };

    // binarize all weights
    struct { const float* src; int8_t* dst; int n; } sj[8] = {
        {w[0], w1s, 256 * 3 * 23}, {w[1], w2s, 256 * 256 * 13},
        {w[2], w3s, 256 * 256 * 7}, {w[3], w4s, 256 * 256 * 5},
        {w[4], w5s, 256 * 256 * 5}, {w[5], w6s, 8 * 256 * 3},
        {fw1, f1s, 512 * 32}, {fw2, f2s, 1000 * 512},
    };
    for (int i = 0; i < 8; ++i)
        sign_w_kernel<<<gridOf(sj[i].n), BLK, 0, stream>>>(sj[i].src, sj[i].dst, sj[i].n);

    // layer 1
    {
        int total = 128 * 256 * 482;
        conv1_kernel<<<gridOf(total), BLK, 0, stream>>>(x, w1s, b[0], sw[0], sb[0], a1);
    }
    // layer 2: Cin=256 K=13 dil=3 pool(3,1): Lin=482 Lconv=446 Lout=149
    {
        int total = 128 * 256 * 149;
        bconv_kernel<256, 13, 3, 3, 1><<<gridOf(total), BLK, 0, stream>>>(
            a1, w2s, b[1], sw[1], sb[1], a2, 256, 482, 446, 149, total);
    }
    // layer 3: K=7 dil=2 pool(3,1): Lin=149 Lconv=137 Lout=46
    {
        int total = 128 * 256 * 46;
        bconv_kernel<256, 7, 2, 3, 1><<<gridOf(total), BLK, 0, stream>>>(
            a2, w3s, b[2], sw[2], sb[2], a3, 256, 149, 137, 46, total);
    }
    // layer 4: K=5 dil=1 no pool: Lin=46 Lconv=42 Lout=42
    {
        int total = 128 * 256 * 42;
        bconv_kernel<256, 5, 1, 1, 0><<<gridOf(total), BLK, 0, stream>>>(
            a3, w4s, b[3], sw[3], sb[3], a4, 256, 46, 42, 42, total);
    }
    // layer 5: K=5 dil=1 pool(3,1): Lin=42 Lconv=38 Lout=13
    {
        int total = 128 * 256 * 13;
        bconv_kernel<256, 5, 1, 3, 1><<<gridOf(total), BLK, 0, stream>>>(
            a4, w5s, b[4], sw[4], sb[4], a5, 256, 42, 38, 13, total);
    }
    // layer 6: Cout=8 K=3 dil=1 pool(3,1): Lin=13 Lconv=11 Lout=4
    {
        int total = 128 * 8 * 4;
        bconv_kernel<256, 3, 1, 3, 1><<<gridOf(total), BLK, 0, stream>>>(
            a5, w6s, b[5], sw[5], sb[5], a6, 8, 13, 11, 4, total);
    }
    // fc1 + fc2
    fc1_kernel<<<gridOf(128 * 512), BLK, 0, stream>>>(a6, f1s, fsw1, fsb1, h1);
    fc2_kernel<<<gridOf(128 * 1000), BLK, 0, stream>>>(h1, f2s, fsw2, fsb2, out);
}

// Round 2
// 1242.774 us; speedup vs baseline: 27.2009x; 27.2009x over previous
//
#include <hip/hip_runtime.h>
#include <cstdint>
#include <cstddef>

typedef unsigned long long u64;

// ---------------------------------------------------------------------------
// Binary AlexNet-1D. bq(w)=0.1*sign(w), bact(x)=sign(x). All binary layers are
// exact integer XNOR-popcount + f64 affine epilogue. Activations bitpacked as
// [N][L][C/64] u64. Conv sum = CIN*K - 2*popc(a^w); maxpool (stride==kernel,
// scale 0.1>0) commutes with the affine map, so pool the integer sums.
// Layer 1 (real f32 input) accumulates in f64 to avoid sign flips near zero.
// ---------------------------------------------------------------------------

// pack conv weights: w[Cout][CIN][K] float -> wpk[K][Cout][CIN/64] (bit = ci&63)
__global__ void packw_kernel(const float* __restrict__ w, u64* __restrict__ wpk,
                             int Cout, int CIN, int K)
{
    int gtid = blockIdx.x * blockDim.x + threadIdx.x;
    int wid = gtid >> 6, lane = gtid & 63;
    int W = CIN >> 6;
    int total = K * Cout * W;
    if (wid >= total) return;
    int wg = wid % W;
    int co = (wid / W) % Cout;
    int k  = wid / (W * Cout);
    int ci = wg * 64 + lane;
    bool sg = w[((size_t)co * CIN + ci) * K + k] >= 0.0f;
    u64 word = __ballot(sg);
    if (lane == 0) wpk[wid] = word;
}

// pack fc weights: w[O][I] float -> wpk[O][I/64]
__global__ void packfc_kernel(const float* __restrict__ w, u64* __restrict__ wpk,
                              int O, int I)
{
    int gtid = blockIdx.x * blockDim.x + threadIdx.x;
    int wid = gtid >> 6, lane = gtid & 63;
    int IW = I >> 6;
    int total = O * IW;
    if (wid >= total) return;
    int o = wid / IW, wg = wid % IW;
    bool sg = w[(size_t)o * I + wg * 64 + lane] >= 0.0f;
    u64 word = __ballot(sg);
    if (lane == 0) wpk[wid] = word;
}

// Layer 1: x[128][3][2560] (f32) conv sign(w1)[256][3][23] dil 7 -> pool(5,2)
// -> scale-bias -> sign -> packed out[128][482][4]. One wave = 64 channels at
// one (n,lp); lane = channel. f64 accumulation (exactness at sign boundary).
__global__ void conv1_kernel(const float* __restrict__ x,
                             const float* __restrict__ w1,
                             const float* __restrict__ b,
                             const float* __restrict__ sw,
                             const float* __restrict__ sb,
                             u64* __restrict__ opk)
{
    const int Lout = 482, Lconv = 2406, Lin = 2560, WOUT = 4;
    int gtid = blockIdx.x * blockDim.x + threadIdx.x;
    int wid = gtid >> 6, lane = gtid & 63;
    int nwaves = 128 * Lout * WOUT;
    if (wid >= nwaves) return;
    int og = wid % WOUT;
    int lp = (wid / WOUT) % Lout;
    int n  = wid / (WOUT * Lout);
    int co = og * 64 + lane;

    // hoist the 69 weight signs into a 69-bit register mask
    u64 m0 = 0, m1 = 0;
    const float* wp = w1 + (size_t)co * 69;
    #pragma unroll
    for (int i = 0; i < 64; ++i) m0 |= (u64)(wp[i] >= 0.0f) << i;
    #pragma unroll
    for (int i = 64; i < 69; ++i) m1 |= (u64)(wp[i] >= 0.0f) << (i - 64);

    const float* xb = x + (size_t)n * 3 * Lin;
    double best = -1e300;
    for (int t = 0; t < 5; ++t) {
        int l = lp * 5 - 2 + t;
        if (l < 0 || l >= Lconv) continue;
        double s = 0.0;
        #pragma unroll
        for (int ci = 0; ci < 3; ++ci) {
            const float* xp = xb + ci * Lin + l;
            #pragma unroll
            for (int kk = 0; kk < 23; ++kk) {
                int i = ci * 23 + kk;
                double xv = (double)xp[kk * 7];
                bool sg = (i < 64) ? ((m0 >> i) & 1ull) : ((m1 >> (i - 64)) & 1ull);
                s += sg ? xv : -xv;
            }
        }
        best = fmax(best, s);
    }
    double conv = 0.1 * best + (double)b[co];
    double v = ((sw[co] >= 0.0f) ? 0.1 : -0.1) * conv + (double)sb[co];
    u64 word = __ballot(v >= 0.0);
    if (lane == 0) opk[wid] = word;   // wid == ((n*Lout+lp)*WOUT+og)
}

// Binary conv layer, bitpacked XNOR-popcount. One wave = 64 output channels at
// one (n,lp); lane = channel. PK==1,PP==0 -> no pool.
template<int K, int DIL, int PK, int PP, int W>
__global__ void bconv_bit_kernel(const u64* __restrict__ apk,  // [N][Lin][W]
                                 const u64* __restrict__ wpk,  // [K][Cout][W]
                                 const float* __restrict__ b,
                                 const float* __restrict__ sw,
                                 const float* __restrict__ sb,
                                 u64* __restrict__ opk,        // [N][Lout][Cout/64]
                                 int Cout, int Lin, int Lconv, int Lout, int nwaves)
{
    int gtid = blockIdx.x * blockDim.x + threadIdx.x;
    int wid = gtid >> 6, lane = gtid & 63;
    if (wid >= nwaves) return;
    const int WOUT_ = 0; (void)WOUT_;
    int WOUT = Cout >> 6;
    int og = wid % WOUT;
    int lp = (wid / WOUT) % Lout;
    int n  = wid / (WOUT * Lout);
    int co = og * 64 + lane;

    const u64* ab = apk + (size_t)n * Lin * W;
    int cnt[PK];
    #pragma unroll
    for (int t = 0; t < PK; ++t) cnt[t] = 0;

    #pragma unroll
    for (int k = 0; k < K; ++k) {
        u64 ww[W];
        #pragma unroll
        for (int w = 0; w < W; ++w)
            ww[w] = wpk[((size_t)k * Cout + co) * W + w];
        #pragma unroll
        for (int t = 0; t < PK; ++t) {
            int l = lp * PK - PP + t;
            if (l < 0 || l >= Lconv) continue;
            const u64* ap = ab + (size_t)(l + k * DIL) * W;
            #pragma unroll
            for (int w = 0; w < W; ++w)
                cnt[t] += __popcll(ap[w] ^ ww[w]);
        }
    }
    const int CINK = W * 64 * K;
    int best = -2147483647;
    #pragma unroll
    for (int t = 0; t < PK; ++t) {
        int l = lp * PK - PP + t;
        if (l < 0 || l >= Lconv) continue;
        int ksum = CINK - 2 * cnt[t];
        best = (ksum > best) ? ksum : best;
    }
    double conv = 0.1 * (double)best + (double)b[co];
    double v = ((sw[co] >= 0.0f) ? 0.1 : -0.1) * conv + (double)sb[co];
    u64 word = __ballot(v >= 0.0);
    if (lane == 0) opk[wid] = word;
}

// Layer 6: Cin=256 packed, Cout=8, K=3, pool(3,1). Thread per (n,co,lp).
// Output unpacked int8 [128][8][4] (feeds reshape(-1,32) = co*4+lp order).
__global__ void bconv6_kernel(const u64* __restrict__ apk,  // [128][13][4]
                              const u64* __restrict__ wpk,  // [3][8][4]
                              const float* __restrict__ b,
                              const float* __restrict__ sw,
                              const float* __restrict__ sb,
                              int8_t* __restrict__ a6)      // [128][8][4]
{
    int idx = blockIdx.x * blockDim.x + threadIdx.x;
    if (idx >= 128 * 8 * 4) return;
    int lp = idx % 4;
    int co = (idx / 4) % 8;
    int n  = idx / 32;
    const u64* ab = apk + (size_t)n * 13 * 4;
    int best = -2147483647;
    for (int t = 0; t < 3; ++t) {
        int l = lp * 3 - 1 + t;
        if (l < 0 || l >= 11) continue;
        int cnt = 0;
        #pragma unroll
        for (int k = 0; k < 3; ++k)
            #pragma unroll
            for (int w = 0; w < 4; ++w)
                cnt += __popcll(ab[(size_t)(l + k) * 4 + w] ^ wpk[((size_t)k * 8 + co) * 4 + w]);
        int ksum = 256 * 3 - 2 * cnt;
        best = (ksum > best) ? ksum : best;
    }
    double conv = 0.1 * (double)best + (double)b[co];
    double v = ((sw[co] >= 0.0f) ? 0.1 : -0.1) * conv + (double)sb[co];
    a6[idx] = (v >= 0.0) ? (int8_t)1 : (int8_t)-1;
}

// FC1: a6[128][32] int8 @ sign(fw1[512][32]) -> affine -> sign -> packed h[128][8]
__global__ void fc1_kernel(const int8_t* __restrict__ a,
                           const float* __restrict__ fw1,
                           const float* __restrict__ fsw,
                           const float* __restrict__ fsb,
                           u64* __restrict__ hpk)
{
    int idx = blockIdx.x * blockDim.x + threadIdx.x;
    if (idx >= 128 * 512) return;
    int o = idx % 512;
    int n = idx / 512;
    int k = 0;
    #pragma unroll
    for (int i = 0; i < 32; ++i) {
        int av = (int)a[n * 32 + i];
        k += (fw1[o * 32 + i] >= 0.0f) ? av : -av;
    }
    double v = ((fsw[o] >= 0.0f) ? 0.1 : -0.1) * (0.1 * (double)k) + (double)fsb[o];
    u64 word = __ballot(v >= 0.0);
    if ((threadIdx.x & 63) == 0) hpk[idx >> 6] = word;  // [n][o/64], n*8+o/64
}

// FC2: h[128][8]u64 xnor fpk2[1000][8] -> affine -> out f32 [128][1000]
__global__ void fc2_kernel(const u64* __restrict__ hpk,
                           const u64* __restrict__ fpk2,
                           const float* __restrict__ fsw,
                           const float* __restrict__ fsb,
                           float* __restrict__ out)
{
    int idx = blockIdx.x * blockDim.x + threadIdx.x;
    if (idx >= 128 * 1000) return;
    int o = idx % 1000;
    int n = idx / 1000;
    int cnt = 0;
    #pragma unroll
    for (int w = 0; w < 8; ++w)
        cnt += __popcll(hpk[n * 8 + w] ^ fpk2[o * 8 + w]);
    int k = 512 - 2 * cnt;
    double v = ((fsw[o] >= 0.0f) ? 0.1 : -0.1) * (0.1 * (double)k) + (double)fsb[o];
    out[idx] = (float)v;
}

extern "C" void kernel_launch(void* const* d_in, const int* in_sizes, int n_in,
                              void* d_out, int out_size, void* d_ws, size_t ws_size,
                              hipStream_t stream) {
    const float* x = (const float*)d_in[0];
    const float *w[6], *b[6], *sw[6], *sb[6];
    for (int i = 0; i < 6; ++i) {
        w[i]  = (const float*)d_in[1 + 4 * i];
        b[i]  = (const float*)d_in[2 + 4 * i];
        sw[i] = (const float*)d_in[3 + 4 * i];
        sb[i] = (const float*)d_in[4 + 4 * i];
    }
    const float* fw1  = (const float*)d_in[25];
    const float* fsw1 = (const float*)d_in[26];
    const float* fsb1 = (const float*)d_in[27];
    const float* fw2  = (const float*)d_in[28];
    const float* fsw2 = (const float*)d_in[29];
    const float* fsb2 = (const float*)d_in[30];
    float* out = (float*)d_out;
    (void)in_sizes; (void)n_in; (void)out_size; (void)ws_size;

    char* wsbase = (char*)d_ws;
    size_t off = 0;
    auto alloc = [&](size_t bytes) -> char* {
        char* p = wsbase + off;
        off = (off + bytes + 255) & ~(size_t)255;
        return p;
    };
    u64* wpk2 = (u64*)alloc((size_t)13 * 256 * 4 * 8);
    u64* wpk3 = (u64*)alloc((size_t)7 * 256 * 4 * 8);
    u64* wpk4 = (u64*)alloc((size_t)5 * 256 * 4 * 8);
    u64* wpk5 = (u64*)alloc((size_t)5 * 256 * 4 * 8);
    u64* wpk6 = (u64*)alloc((size_t)3 * 8 * 4 * 8);
    u64* fpk2 = (u64*)alloc((size_t)1000 * 8 * 8);
    u64* a1   = (u64*)alloc((size_t)128 * 482 * 4 * 8);
    u64* a2   = (u64*)alloc((size_t)128 * 149 * 4 * 8);
    u64* a3   = (u64*)alloc((size_t)128 * 46 * 4 * 8);
    u64* a4   = (u64*)alloc((size_t)128 * 42 * 4 * 8);
    u64* a5   = (u64*)alloc((size_t)128 * 13 * 4 * 8);
    int8_t* a6 = (int8_t*)alloc((size_t)128 * 32);
    u64* hpk  = (u64*)alloc((size_t)128 * 8 * 8);

    const int BLK = 256;
    auto blocksForWaves = [](int nwaves) { return dim3((unsigned)((nwaves * 64 + 255) / 256)); };
    auto blocksForThreads = [](int n) { return dim3((unsigned)((n + 255) / 256)); };

    // weight packing
    packw_kernel<<<blocksForWaves(13 * 256 * 4), BLK, 0, stream>>>(w[1], wpk2, 256, 256, 13);
    packw_kernel<<<blocksForWaves(7 * 256 * 4),  BLK, 0, stream>>>(w[2], wpk3, 256, 256, 7);
    packw_kernel<<<blocksForWaves(5 * 256 * 4),  BLK, 0, stream>>>(w[3], wpk4, 256, 256, 5);
    packw_kernel<<<blocksForWaves(5 * 256 * 4),  BLK, 0, stream>>>(w[4], wpk5, 256, 256, 5);
    packw_kernel<<<blocksForWaves(3 * 8 * 4),    BLK, 0, stream>>>(w[5], wpk6, 8, 256, 3);
    packfc_kernel<<<blocksForWaves(1000 * 8),    BLK, 0, stream>>>(fw2, fpk2, 1000, 512);

    // layer 1 (f64, packs output)
    conv1_kernel<<<blocksForWaves(128 * 482 * 4), BLK, 0, stream>>>(x, w[0], b[0], sw[0], sb[0], a1);

    // layer 2: K=13 dil=3 pool(3,1): Lin=482 Lconv=446 Lout=149
    {
        int nw = 128 * 149 * 4;
        bconv_bit_kernel<13, 3, 3, 1, 4><<<blocksForWaves(nw), BLK, 0, stream>>>(
            a1, wpk2, b[1], sw[1], sb[1], a2, 256, 482, 446, 149, nw);
    }
    // layer 3: K=7 dil=2 pool(3,1): Lin=149 Lconv=137 Lout=46
    {
        int nw = 128 * 46 * 4;
        bconv_bit_kernel<7, 2, 3, 1, 4><<<blocksForWaves(nw), BLK, 0, stream>>>(
            a2, wpk3, b[2], sw[2], sb[2], a3, 256, 149, 137, 46, nw);
    }
    // layer 4: K=5 dil=1 no pool: Lin=46 Lconv=42 Lout=42
    {
        int nw = 128 * 42 * 4;
        bconv_bit_kernel<5, 1, 1, 0, 4><<<blocksForWaves(nw), BLK, 0, stream>>>(
            a3, wpk4, b[3], sw[3], sb[3], a4, 256, 46, 42, 42, nw);
    }
    // layer 5: K=5 dil=1 pool(3,1): Lin=42 Lconv=38 Lout=13
    {
        int nw = 128 * 13 * 4;
        bconv_bit_kernel<5, 1, 3, 1, 4><<<blocksForWaves(nw), BLK, 0, stream>>>(
            a4, wpk5, b[4], sw[4], sb[4], a5, 256, 42, 38, 13, nw);
    }
    // layer 6: Cout=8 K=3 pool(3,1): Lin=13 Lconv=11 Lout=4
    bconv6_kernel<<<blocksForThreads(128 * 8 * 4), BLK, 0, stream>>>(a5, wpk6, b[5], sw[5], sb[5], a6);

    // fc1 + fc2
    fc1_kernel<<<blocksForThreads(128 * 512), BLK, 0, stream>>>(a6, fw1, fsw1, fsb1, hpk);
    fc2_kernel<<<blocksForThreads(128 * 1000), BLK, 0, stream>>>(hpk, fpk2, fsw2, fsb2, out);
}

// Round 3
// 680.145 us; speedup vs baseline: 49.7020x; 1.8272x over previous
//
#include <hip/hip_runtime.h>
#include <cstdint>
#include <cstddef>

typedef unsigned long long u64;
typedef uint32_t u32;

// ---------------------------------------------------------------------------
// Binary AlexNet-1D. bq(w)=0.1*sign(w), bact(x)=sign(x). All binary layers are
// exact integer XNOR-popcount + f64 affine epilogue. Activations bitpacked as
// [N][L][C/64] u64. Conv sum = CIN*K - 2*popc(a^w); maxpool (stride==kernel,
// scale 0.1>0) commutes with the affine map, so pool the integer sums.
// Layer 1 (real f32 input): fast f32 FMA pass (sign folded into +-1.0f scalar
// multiplier) + uncertainty margin; rare near-zero outputs are recomputed in
// f64 by a fixup kernel, so sign decisions remain f64-exact.
// ---------------------------------------------------------------------------

#define CONV1_MARGIN 1e-4f

// pack conv weights: w[Cout][CIN][K] float -> wpk[K][Cout][CIN/64] (bit = ci&63)
__global__ void packw_kernel(const float* __restrict__ w, u64* __restrict__ wpk,
                             int Cout, int CIN, int K)
{
    int gtid = blockIdx.x * blockDim.x + threadIdx.x;
    int wid = gtid >> 6, lane = gtid & 63;
    int W = CIN >> 6;
    int total = K * Cout * W;
    if (wid >= total) return;
    int wg = wid % W;
    int co = (wid / W) % Cout;
    int k  = wid / (W * Cout);
    int ci = wg * 64 + lane;
    bool sg = w[((size_t)co * CIN + ci) * K + k] >= 0.0f;
    u64 word = __ballot(sg);
    if (lane == 0) wpk[wid] = word;
}

// pack fc weights: w[O][I] float -> wpk[O][I/64]
__global__ void packfc_kernel(const float* __restrict__ w, u64* __restrict__ wpk,
                              int O, int I)
{
    int gtid = blockIdx.x * blockDim.x + threadIdx.x;
    int wid = gtid >> 6, lane = gtid & 63;
    int IW = I >> 6;
    int total = O * IW;
    if (wid >= total) return;
    int o = wid / IW, wg = wid % IW;
    bool sg = w[(size_t)o * I + wg * 64 + lane] >= 0.0f;
    u64 word = __ballot(sg);
    if (lane == 0) wpk[wid] = word;
}

// layer-1 weight signs as f32 +-1.0: sgnf[i][co], i = ci*23+kk, [69][256]
__global__ void pack_sgn1_kernel(const float* __restrict__ w1, float* __restrict__ sgnf)
{
    int idx = blockIdx.x * blockDim.x + threadIdx.x;
    if (idx >= 69 * 256) return;
    int co = idx & 255, i = idx >> 8;
    sgnf[i * 256 + co] = (w1[co * 69 + i] >= 0.0f) ? 1.0f : -1.0f;
}

// Layer 1 pass 1 (f32): lane = conv position l, inner loop = 32 channels
// (chunk of 256). Phase 1: s(l, co) = sum_i sgn * x[l + off_i] via v_fmac with
// wave-uniform sgn. Phase 2: pool max over 5 positions (LDS), affine, sign,
// ballot-pack bits + uncertainty flags.
// grid: (n=128, lblk=10, chunk=8); block covers l in [250*lblk-2, 250*lblk+254),
// produces lp in [50*lblk, 50*lblk+50).
__global__ __launch_bounds__(256) void conv1_pass1_kernel(
    const float* __restrict__ x, const float* __restrict__ sgnf,
    const float* __restrict__ b, const float* __restrict__ sw,
    const float* __restrict__ sb,
    u32* __restrict__ opk32, u32* __restrict__ uflag)
{
    __shared__ float s_lds[32][256];
    const int Lconv = 2406, Lin = 2560;
    int n = blockIdx.x;
    int bl = blockIdx.y;
    int chunk = blockIdx.z;
    int tid = threadIdx.x;

    int l = 250 * bl - 2 + tid;
    int lc = min(max(l, 0), Lconv - 1);
    const float* xb = x + (size_t)n * 3 * Lin;
    const float* sgc = sgnf + chunk * 32;

    float acc[32];
    #pragma unroll
    for (int c = 0; c < 32; ++c) acc[c] = 0.0f;

    #pragma unroll
    for (int ci = 0; ci < 3; ++ci) {
        const float* xp = xb + ci * Lin + lc;
        #pragma unroll
        for (int kk = 0; kk < 23; ++kk) {
            float xv = xp[kk * 7];
            int i = ci * 23 + kk;
            #pragma unroll
            for (int c = 0; c < 32; ++c)
                acc[c] = fmaf(xv, sgc[i * 256 + c], acc[c]);
        }
    }
    #pragma unroll
    for (int c = 0; c < 32; ++c) s_lds[c][tid] = acc[c];
    __syncthreads();

    // phase 2: pooling + affine + sign + pack
    int co_l = tid & 31;
    int co = chunk * 32 + co_l;
    float bc = b[co];
    float swc = (sw[co] >= 0.0f) ? 0.1f : -0.1f;
    float sbc = sb[co];
    int lane = tid & 63;

    for (int it = 0; it < 7; ++it) {
        int lp_local = (tid >> 5) + it * 8;
        int lp = bl * 50 + lp_local;
        bool valid = (lp_local < 50) && (lp < 482);
        bool bit = false, unc = false;
        if (valid) {
            float best = -1e30f;
            #pragma unroll
            for (int t = 0; t < 5; ++t) {
                int gl = 5 * lp - 2 + t;
                if (gl < 0 || gl >= Lconv) continue;
                int r = gl - (250 * bl - 2);
                best = fmaxf(best, s_lds[co_l][r]);
            }
            float v = swc * (0.1f * best + bc) + sbc;
            bit = (v >= 0.0f);
            unc = (fabsf(v) < CONV1_MARGIN);
        }
        u64 wb = __ballot(bit);
        u64 wu = __ballot(unc);
        if (valid && co_l == 0) {
            u32 wordb = (lane < 32) ? (u32)wb : (u32)(wb >> 32);
            u32 wordu = (lane < 32) ? (u32)wu : (u32)(wu >> 32);
            size_t widx = ((size_t)n * 482 + lp) * 8 + chunk;
            opk32[widx] = wordb;
            uflag[widx] = wordu;
        }
    }
}

// Fixup: thread per packed u32 word; if any uncertainty bit set, recompute
// those channels in f64 (exact) and patch the word.
__global__ void conv1_fixup_kernel(const float* __restrict__ x,
                                   const float* __restrict__ w1,
                                   const float* __restrict__ b,
                                   const float* __restrict__ sw,
                                   const float* __restrict__ sb,
                                   const u32* __restrict__ uflag,
                                   u32* __restrict__ opk32)
{
    int idx = blockIdx.x * blockDim.x + threadIdx.x;
    if (idx >= 128 * 482 * 8) return;
    u32 f = uflag[idx];
    if (f == 0) return;
    int chunk = idx & 7;
    int lp = (idx >> 3) % 482;
    int n = idx / (8 * 482);
    u32 word = opk32[idx];
    const float* xb = x + (size_t)n * 3 * 2560;
    while (f) {
        int c = __ffs(f) - 1;
        f &= f - 1;
        int co = chunk * 32 + c;
        const float* wp = w1 + (size_t)co * 69;
        double best = -1e300;
        for (int t = 0; t < 5; ++t) {
            int gl = 5 * lp - 2 + t;
            if (gl < 0 || gl >= 2406) continue;
            double s = 0.0;
            for (int i = 0; i < 69; ++i) {
                int ci = i / 23, kk = i % 23;
                double xv = (double)xb[ci * 2560 + gl + kk * 7];
                s += (wp[i] >= 0.0f) ? xv : -xv;
            }
            best = fmax(best, s);
        }
        double v = ((sw[co] >= 0.0f) ? 0.1 : -0.1) * (0.1 * best + (double)b[co]) + (double)sb[co];
        u32 bit = (v >= 0.0) ? 1u : 0u;
        word = (word & ~(1u << c)) | (bit << c);
    }
    opk32[idx] = word;
}

// Binary conv layer, bitpacked XNOR-popcount. One wave = 64 output channels at
// one (n,lp); lane = channel. PK==1,PP==0 -> no pool.
template<int K, int DIL, int PK, int PP, int W>
__global__ void bconv_bit_kernel(const u64* __restrict__ apk,  // [N][Lin][W]
                                 const u64* __restrict__ wpk,  // [K][Cout][W]
                                 const float* __restrict__ b,
                                 const float* __restrict__ sw,
                                 const float* __restrict__ sb,
                                 u64* __restrict__ opk,        // [N][Lout][Cout/64]
                                 int Cout, int Lin, int Lconv, int Lout, int nwaves)
{
    int gtid = blockIdx.x * blockDim.x + threadIdx.x;
    int wid = gtid >> 6, lane = gtid & 63;
    if (wid >= nwaves) return;
    int WOUT = Cout >> 6;
    int og = wid % WOUT;
    int lp = (wid / WOUT) % Lout;
    int n  = wid / (WOUT * Lout);
    int co = og * 64 + lane;

    const u64* ab = apk + (size_t)n * Lin * W;
    int cnt[PK];
    #pragma unroll
    for (int t = 0; t < PK; ++t) cnt[t] = 0;

    #pragma unroll
    for (int k = 0; k < K; ++k) {
        u64 ww[W];
        #pragma unroll
        for (int w = 0; w < W; ++w)
            ww[w] = wpk[((size_t)k * Cout + co) * W + w];
        #pragma unroll
        for (int t = 0; t < PK; ++t) {
            int l = lp * PK - PP + t;
            if (l < 0 || l >= Lconv) continue;
            const u64* ap = ab + (size_t)(l + k * DIL) * W;
            #pragma unroll
            for (int w = 0; w < W; ++w)
                cnt[t] += __popcll(ap[w] ^ ww[w]);
        }
    }
    const int CINK = W * 64 * K;
    int best = -2147483647;
    #pragma unroll
    for (int t = 0; t < PK; ++t) {
        int l = lp * PK - PP + t;
        if (l < 0 || l >= Lconv) continue;
        int ksum = CINK - 2 * cnt[t];
        best = (ksum > best) ? ksum : best;
    }
    double conv = 0.1 * (double)best + (double)b[co];
    double v = ((sw[co] >= 0.0f) ? 0.1 : -0.1) * conv + (double)sb[co];
    u64 word = __ballot(v >= 0.0);
    if (lane == 0) opk[wid] = word;
}

// Layer 6: Cin=256 packed, Cout=8, K=3, pool(3,1). Thread per (n,co,lp).
__global__ void bconv6_kernel(const u64* __restrict__ apk,  // [128][13][4]
                              const u64* __restrict__ wpk,  // [3][8][4]
                              const float* __restrict__ b,
                              const float* __restrict__ sw,
                              const float* __restrict__ sb,
                              int8_t* __restrict__ a6)      // [128][8][4]
{
    int idx = blockIdx.x * blockDim.x + threadIdx.x;
    if (idx >= 128 * 8 * 4) return;
    int lp = idx % 4;
    int co = (idx / 4) % 8;
    int n  = idx / 32;
    const u64* ab = apk + (size_t)n * 13 * 4;
    int best = -2147483647;
    for (int t = 0; t < 3; ++t) {
        int l = lp * 3 - 1 + t;
        if (l < 0 || l >= 11) continue;
        int cnt = 0;
        #pragma unroll
        for (int k = 0; k < 3; ++k)
            #pragma unroll
            for (int w = 0; w < 4; ++w)
                cnt += __popcll(ab[(size_t)(l + k) * 4 + w] ^ wpk[((size_t)k * 8 + co) * 4 + w]);
        int ksum = 256 * 3 - 2 * cnt;
        best = (ksum > best) ? ksum : best;
    }
    double conv = 0.1 * (double)best + (double)b[co];
    double v = ((sw[co] >= 0.0f) ? 0.1 : -0.1) * conv + (double)sb[co];
    a6[idx] = (v >= 0.0) ? (int8_t)1 : (int8_t)-1;
}

// FC1: a6[128][32] int8 @ sign(fw1[512][32]) -> affine -> sign -> packed h[128][8]
__global__ void fc1_kernel(const int8_t* __restrict__ a,
                           const float* __restrict__ fw1,
                           const float* __restrict__ fsw,
                           const float* __restrict__ fsb,
                           u64* __restrict__ hpk)
{
    int idx = blockIdx.x * blockDim.x + threadIdx.x;
    if (idx >= 128 * 512) return;
    int o = idx % 512;
    int n = idx / 512;
    int k = 0;
    #pragma unroll
    for (int i = 0; i < 32; ++i) {
        int av = (int)a[n * 32 + i];
        k += (fw1[o * 32 + i] >= 0.0f) ? av : -av;
    }
    double v = ((fsw[o] >= 0.0f) ? 0.1 : -0.1) * (0.1 * (double)k) + (double)fsb[o];
    u64 word = __ballot(v >= 0.0);
    if ((threadIdx.x & 63) == 0) hpk[idx >> 6] = word;
}

// FC2: h[128][8]u64 xnor fpk2[1000][8] -> affine -> out f32 [128][1000]
__global__ void fc2_kernel(const u64* __restrict__ hpk,
                           const u64* __restrict__ fpk2,
                           const float* __restrict__ fsw,
                           const float* __restrict__ fsb,
                           float* __restrict__ out)
{
    int idx = blockIdx.x * blockDim.x + threadIdx.x;
    if (idx >= 128 * 1000) return;
    int o = idx % 1000;
    int n = idx / 1000;
    int cnt = 0;
    #pragma unroll
    for (int w = 0; w < 8; ++w)
        cnt += __popcll(hpk[n * 8 + w] ^ fpk2[o * 8 + w]);
    int k = 512 - 2 * cnt;
    double v = ((fsw[o] >= 0.0f) ? 0.1 : -0.1) * (0.1 * (double)k) + (double)fsb[o];
    out[idx] = (float)v;
}

extern "C" void kernel_launch(void* const* d_in, const int* in_sizes, int n_in,
                              void* d_out, int out_size, void* d_ws, size_t ws_size,
                              hipStream_t stream) {
    const float* x = (const float*)d_in[0];
    const float *w[6], *b[6], *sw[6], *sb[6];
    for (int i = 0; i < 6; ++i) {
        w[i]  = (const float*)d_in[1 + 4 * i];
        b[i]  = (const float*)d_in[2 + 4 * i];
        sw[i] = (const float*)d_in[3 + 4 * i];
        sb[i] = (const float*)d_in[4 + 4 * i];
    }
    const float* fw1  = (const float*)d_in[25];
    const float* fsw1 = (const float*)d_in[26];
    const float* fsb1 = (const float*)d_in[27];
    const float* fw2  = (const float*)d_in[28];
    const float* fsw2 = (const float*)d_in[29];
    const float* fsb2 = (const float*)d_in[30];
    float* out = (float*)d_out;
    (void)in_sizes; (void)n_in; (void)out_size; (void)ws_size;

    char* wsbase = (char*)d_ws;
    size_t off = 0;
    auto alloc = [&](size_t bytes) -> char* {
        char* p = wsbase + off;
        off = (off + bytes + 255) & ~(size_t)255;
        return p;
    };
    u64* wpk2 = (u64*)alloc((size_t)13 * 256 * 4 * 8);
    u64* wpk3 = (u64*)alloc((size_t)7 * 256 * 4 * 8);
    u64* wpk4 = (u64*)alloc((size_t)5 * 256 * 4 * 8);
    u64* wpk5 = (u64*)alloc((size_t)5 * 256 * 4 * 8);
    u64* wpk6 = (u64*)alloc((size_t)3 * 8 * 4 * 8);
    u64* fpk2 = (u64*)alloc((size_t)1000 * 8 * 8);
    float* sgnf = (float*)alloc((size_t)69 * 256 * 4);
    u32* uflag  = (u32*)alloc((size_t)128 * 482 * 8 * 4);
    u64* a1   = (u64*)alloc((size_t)128 * 482 * 4 * 8);
    u64* a2   = (u64*)alloc((size_t)128 * 149 * 4 * 8);
    u64* a3   = (u64*)alloc((size_t)128 * 46 * 4 * 8);
    u64* a4   = (u64*)alloc((size_t)128 * 42 * 4 * 8);
    u64* a5   = (u64*)alloc((size_t)128 * 13 * 4 * 8);
    int8_t* a6 = (int8_t*)alloc((size_t)128 * 32);
    u64* hpk  = (u64*)alloc((size_t)128 * 8 * 8);
    u32* opk32 = (u32*)a1;  // same bytes: u64 word og = chunks (2og, 2og+1)

    const int BLK = 256;
    auto blocksForWaves = [](int nwaves) { return dim3((unsigned)((nwaves * 64 + 255) / 256)); };
    auto blocksForThreads = [](int n) { return dim3((unsigned)((n + 255) / 256)); };

    // weight packing
    packw_kernel<<<blocksForWaves(13 * 256 * 4), BLK, 0, stream>>>(w[1], wpk2, 256, 256, 13);
    packw_kernel<<<blocksForWaves(7 * 256 * 4),  BLK, 0, stream>>>(w[2], wpk3, 256, 256, 7);
    packw_kernel<<<blocksForWaves(5 * 256 * 4),  BLK, 0, stream>>>(w[3], wpk4, 256, 256, 5);
    packw_kernel<<<blocksForWaves(5 * 256 * 4),  BLK, 0, stream>>>(w[4], wpk5, 256, 256, 5);
    packw_kernel<<<blocksForWaves(3 * 8 * 4),    BLK, 0, stream>>>(w[5], wpk6, 8, 256, 3);
    packfc_kernel<<<blocksForWaves(1000 * 8),    BLK, 0, stream>>>(fw2, fpk2, 1000, 512);
    pack_sgn1_kernel<<<blocksForThreads(69 * 256), BLK, 0, stream>>>(w[0], sgnf);

    // layer 1: fast f32 pass + f64 fixup of near-zero outputs
    conv1_pass1_kernel<<<dim3(128, 10, 8), BLK, 0, stream>>>(
        x, sgnf, b[0], sw[0], sb[0], opk32, uflag);
    conv1_fixup_kernel<<<blocksForThreads(128 * 482 * 8), BLK, 0, stream>>>(
        x, w[0], b[0], sw[0], sb[0], uflag, opk32);

    // layer 2: K=13 dil=3 pool(3,1): Lin=482 Lconv=446 Lout=149
    {
        int nw = 128 * 149 * 4;
        bconv_bit_kernel<13, 3, 3, 1, 4><<<blocksForWaves(nw), BLK, 0, stream>>>(
            a1, wpk2, b[1], sw[1], sb[1], a2, 256, 482, 446, 149, nw);
    }
    // layer 3: K=7 dil=2 pool(3,1): Lin=149 Lconv=137 Lout=46
    {
        int nw = 128 * 46 * 4;
        bconv_bit_kernel<7, 2, 3, 1, 4><<<blocksForWaves(nw), BLK, 0, stream>>>(
            a2, wpk3, b[2], sw[2], sb[2], a3, 256, 149, 137, 46, nw);
    }
    // layer 4: K=5 dil=1 no pool: Lin=46 Lconv=42 Lout=42
    {
        int nw = 128 * 42 * 4;
        bconv_bit_kernel<5, 1, 1, 0, 4><<<blocksForWaves(nw), BLK, 0, stream>>>(
            a3, wpk4, b[3], sw[3], sb[3], a4, 256, 46, 42, 42, nw);
    }
    // layer 5: K=5 dil=1 pool(3,1): Lin=42 Lconv=38 Lout=13
    {
        int nw = 128 * 13 * 4;
        bconv_bit_kernel<5, 1, 3, 1, 4><<<blocksForWaves(nw), BLK, 0, stream>>>(
            a4, wpk5, b[4], sw[4], sb[4], a5, 256, 42, 38, 13, nw);
    }
    // layer 6: Cout=8 K=3 pool(3,1): Lin=13 Lconv=11 Lout=4
    bconv6_kernel<<<blocksForThreads(128 * 8 * 4), BLK, 0, stream>>>(a5, wpk6, b[5], sw[5], sb[5], a6);

    // fc1 + fc2
    fc1_kernel<<<blocksForThreads(128 * 512), BLK, 0, stream>>>(a6, fw1, fsw1, fsb1, hpk);
    fc2_kernel<<<blocksForThreads(128 * 1000), BLK, 0, stream>>>(hpk, fpk2, fsw2, fsb2, out);
}

// Round 4
// 394.323 us; speedup vs baseline: 85.7280x; 1.7248x over previous
//
#include <hip/hip_runtime.h>
#include <cstdint>
#include <cstddef>

typedef unsigned long long u64;
typedef uint32_t u32;
typedef uint16_t u16;

// ---------------------------------------------------------------------------
// Binary AlexNet-1D. bq(w)=0.1*sign(w), bact(x)=sign(x). All binary layers are
// exact integer XNOR-popcount + f64 affine epilogue. Activations bitpacked as
// [N][L][C/64] u64. Conv sum = CIN*K - 2*popc(a^w); maxpool (stride==kernel,
// scale 0.1>0) commutes with the affine map, so pool the integer sums.
// Layer 1 (real f32 input): fast f32 FMA pass (sign folded into +-1.0f
// wave-uniform multiplier) + uncertainty margin; near-zero outputs are
// recomputed in f64 by a fixup kernel, so sign decisions stay f64-exact.
// ---------------------------------------------------------------------------

#define CONV1_MARGIN 1e-4f

// -------------------- merged weight packing --------------------
// packs w[Cout][CIN][K] float -> wpk[K][Cout][CIN/64]; fc layers use K=1.
struct PackJob { const float* src; u64* dst; int Cout, CIN, K, waveBase; };
struct PackJobs { PackJob j[6]; int totalWaves; };

__global__ void pack_all_kernel(PackJobs P)
{
    int gtid = blockIdx.x * blockDim.x + threadIdx.x;
    int wid = gtid >> 6, lane = gtid & 63;
    if (wid >= P.totalWaves) return;
    int jj = 0;
    #pragma unroll
    for (int i = 1; i < 6; ++i) if (wid >= P.j[i].waveBase) jj = i;
    PackJob job = P.j[jj];
    int lw = wid - job.waveBase;
    int W = job.CIN >> 6;
    int wg = lw % W;
    int co = (lw / W) % job.Cout;
    int k  = lw / (W * job.Cout);
    int ci = wg * 64 + lane;
    bool sg = job.src[((size_t)co * job.CIN + ci) * job.K + k] >= 0.0f;
    u64 word = __ballot(sg);
    if (lane == 0) job.dst[lw] = word;
}

// layer-1 weight signs as f32 +-1.0: sgnf[i][co], i = ci*23+kk, [69][256]
__global__ void pack_sgn1_kernel(const float* __restrict__ w1, float* __restrict__ sgnf)
{
    int idx = blockIdx.x * blockDim.x + threadIdx.x;
    if (idx >= 69 * 256) return;
    int co = idx & 255, i = idx >> 8;
    sgnf[i * 256 + co] = (w1[co * 69 + i] >= 0.0f) ? 1.0f : -1.0f;
}

// -------------------- layer 1 --------------------
// Pass 1 (f32): lane = conv position l, inner loop = 16 channels (chunk of
// 256). Phase 1: s(l,co) = sum_i sgn*x[l+off_i] via v_fmac with wave-uniform
// sgn. Phase 2: pool max over 5 positions (LDS, XOR-swizzled banks), affine,
// sign, ballot-pack u16 bit/uncertainty words.
// grid: (n=128, bl=10, chunk=16); block covers l in [250*bl-2, 250*bl+254),
// produces lp in [50*bl, 50*bl+50).
__global__ __launch_bounds__(256) void conv1_pass1_kernel(
    const float* __restrict__ x, const float* __restrict__ sgnf,
    const float* __restrict__ b, const float* __restrict__ sw,
    const float* __restrict__ sb,
    u16* __restrict__ opk16, u16* __restrict__ uflag16)
{
    __shared__ float s_lds[16 * 256];   // [c][l'], col swizzled by ^c
    const int Lconv = 2406, Lin = 2560;
    int n = blockIdx.x;
    int bl = blockIdx.y;
    int chunk = blockIdx.z;
    int tid = threadIdx.x;

    int l = 250 * bl - 2 + tid;
    int lc = min(max(l, 0), Lconv - 1);
    const float* xb = x + (size_t)n * 3 * Lin;
    const float* sgc = sgnf + chunk * 16;

    float acc[16];
    #pragma unroll
    for (int c = 0; c < 16; ++c) acc[c] = 0.0f;

    #pragma unroll
    for (int ci = 0; ci < 3; ++ci) {
        const float* xp = xb + ci * Lin + lc;
        #pragma unroll
        for (int kk = 0; kk < 23; ++kk) {
            float xv = xp[kk * 7];
            int i = ci * 23 + kk;
            #pragma unroll
            for (int c = 0; c < 16; ++c)
                acc[c] = fmaf(xv, sgc[i * 256 + c], acc[c]);
        }
    }
    #pragma unroll
    for (int c = 0; c < 16; ++c) s_lds[c * 256 + (tid ^ c)] = acc[c];
    __syncthreads();

    // phase 2: pooling + affine + sign + pack (u16 granularity)
    int co_l = tid & 15;
    int co = chunk * 16 + co_l;
    float bc = b[co];
    float swc = (sw[co] >= 0.0f) ? 0.1f : -0.1f;
    float sbc = sb[co];
    int lane = tid & 63;

    #pragma unroll
    for (int it = 0; it < 4; ++it) {
        int lp_local = (tid >> 4) + it * 16;
        int lp = bl * 50 + lp_local;
        bool valid = (lp_local < 50) && (lp < 482);
        bool bit = false, unc = false;
        if (valid) {
            float best = -1e30f;
            #pragma unroll
            for (int t = 0; t < 5; ++t) {
                int gl = 5 * lp - 2 + t;
                if (gl < 0 || gl >= Lconv) continue;
                int r = gl - (250 * bl - 2);
                best = fmaxf(best, s_lds[co_l * 256 + (r ^ co_l)]);
            }
            float v = swc * (0.1f * best + bc) + sbc;
            bit = (v >= 0.0f);
            unc = (fabsf(v) < CONV1_MARGIN);
        }
        u64 wb = __ballot(bit);
        u64 wu = __ballot(unc);
        if (valid && co_l == 0) {
            int grp = (lane >> 4);               // lp-subgroup within wave
            u16 wordb = (u16)((wb >> (16 * grp)) & 0xFFFFull);
            u16 wordu = (u16)((wu >> (16 * grp)) & 0xFFFFull);
            size_t widx = ((size_t)n * 482 + lp) * 16 + chunk;
            opk16[widx] = wordb;
            uflag16[widx] = wordu;
        }
    }
}

// Fixup: thread per packed u16 word; recompute flagged channels in f64.
__global__ void conv1_fixup_kernel(const float* __restrict__ x,
                                   const float* __restrict__ w1,
                                   const float* __restrict__ b,
                                   const float* __restrict__ sw,
                                   const float* __restrict__ sb,
                                   const u16* __restrict__ uflag16,
                                   u16* __restrict__ opk16)
{
    int idx = blockIdx.x * blockDim.x + threadIdx.x;
    if (idx >= 128 * 482 * 16) return;
    u32 f = uflag16[idx];
    if (f == 0) return;
    int chunk = idx & 15;
    int lp = (idx >> 4) % 482;
    int n = idx / (16 * 482);
    u32 word = opk16[idx];
    const float* xb = x + (size_t)n * 3 * 2560;
    while (f) {
        int c = __ffs(f) - 1;
        f &= f - 1;
        int co = chunk * 16 + c;
        const float* wp = w1 + (size_t)co * 69;
        double best = -1e300;
        for (int t = 0; t < 5; ++t) {
            int gl = 5 * lp - 2 + t;
            if (gl < 0 || gl >= 2406) continue;
            double s = 0.0;
            #pragma unroll
            for (int ci = 0; ci < 3; ++ci) {
                const float* xp = xb + ci * 2560 + gl;
                const float* wq = wp + ci * 23;
                #pragma unroll
                for (int kk = 0; kk < 23; ++kk) {
                    double xv = (double)xp[kk * 7];
                    s += (wq[kk] >= 0.0f) ? xv : -xv;
                }
            }
            best = fmax(best, s);
        }
        double v = ((sw[co] >= 0.0f) ? 0.1 : -0.1) * (0.1 * best + (double)b[co]) + (double)sb[co];
        u32 bit = (v >= 0.0) ? 1u : 0u;
        word = (word & ~(1u << c)) | (bit << c);
    }
    opk16[idx] = word;
}

// -------------------- binary conv layers (XNOR-popcount) --------------------
// One wave = 64 output channels x LPW pooled positions at one (n,og).
// k-loop outermost so per-lane weights load once per k for all LPW*PK taps.
template<int K, int DIL, int PK, int PP, int W, int LPW>
__global__ void bconv_bit_kernel(const u64* __restrict__ apk,  // [N][Lin][W]
                                 const u64* __restrict__ wpk,  // [K][Cout][W]
                                 const float* __restrict__ b,
                                 const float* __restrict__ sw,
                                 const float* __restrict__ sb,
                                 u64* __restrict__ opk,        // [N][Lout][Cout/64]
                                 int Cout, int Lin, int Lconv, int Lout,
                                 int NLPG, int nwaves)
{
    int wid = __builtin_amdgcn_readfirstlane(
        (int)(blockIdx.x * (blockDim.x >> 6)) + (int)(threadIdx.x >> 6));
    int lane = threadIdx.x & 63;
    if (wid >= nwaves) return;
    int WOUT = Cout >> 6;
    int og = wid % WOUT;
    int lpg = (wid / WOUT) % NLPG;
    int n  = wid / (WOUT * NLPG);
    int lp0 = lpg * LPW;
    int co = og * 64 + lane;

    const u64* ab = apk + (size_t)n * Lin * W;
    int cnt[LPW][PK];
    #pragma unroll
    for (int j = 0; j < LPW; ++j)
        #pragma unroll
        for (int t = 0; t < PK; ++t) cnt[j][t] = 0;

    #pragma unroll
    for (int k = 0; k < K; ++k) {
        u64 ww[W];
        #pragma unroll
        for (int w = 0; w < W; ++w)
            ww[w] = wpk[((size_t)k * Cout + co) * W + w];
        #pragma unroll
        for (int j = 0; j < LPW; ++j) {
            int lp = lp0 + j;
            #pragma unroll
            for (int t = 0; t < PK; ++t) {
                int l = lp * PK - PP + t;
                if (lp >= Lout || l < 0 || l >= Lconv) continue;
                const u64* ap = ab + (size_t)(l + k * DIL) * W;
                #pragma unroll
                for (int w = 0; w < W; ++w)
                    cnt[j][t] += __popcll(ap[w] ^ ww[w]);
            }
        }
    }
    const int CINK = W * 64 * K;
    #pragma unroll
    for (int j = 0; j < LPW; ++j) {
        int lp = lp0 + j;
        int best = -2147483647;
        #pragma unroll
        for (int t = 0; t < PK; ++t) {
            int l = lp * PK - PP + t;
            if (l < 0 || l >= Lconv) continue;
            int ksum = CINK - 2 * cnt[j][t];
            best = (ksum > best) ? ksum : best;
        }
        bool bit = false;
        if (lp < Lout) {
            double conv = 0.1 * (double)best + (double)b[co];
            double v = ((sw[co] >= 0.0f) ? 0.1 : -0.1) * conv + (double)sb[co];
            bit = (v >= 0.0);
        }
        u64 word = __ballot(bit);
        if (lp < Lout && lane == 0)
            opk[((size_t)n * Lout + lp) * WOUT + og] = word;
    }
}

// Layer 6: Cin=256 packed, Cout=8, K=3, pool(3,1). Thread per (n,co,lp).
__global__ void bconv6_kernel(const u64* __restrict__ apk,  // [128][13][4]
                              const u64* __restrict__ wpk,  // [3][8][4]
                              const float* __restrict__ b,
                              const float* __restrict__ sw,
                              const float* __restrict__ sb,
                              int8_t* __restrict__ a6)      // [128][8][4]
{
    int idx = blockIdx.x * blockDim.x + threadIdx.x;
    if (idx >= 128 * 8 * 4) return;
    int lp = idx % 4;
    int co = (idx / 4) % 8;
    int n  = idx / 32;
    const u64* ab = apk + (size_t)n * 13 * 4;
    int best = -2147483647;
    for (int t = 0; t < 3; ++t) {
        int l = lp * 3 - 1 + t;
        if (l < 0 || l >= 11) continue;
        int cnt = 0;
        #pragma unroll
        for (int k = 0; k < 3; ++k)
            #pragma unroll
            for (int w = 0; w < 4; ++w)
                cnt += __popcll(ab[(size_t)(l + k) * 4 + w] ^ wpk[((size_t)k * 8 + co) * 4 + w]);
        int ksum = 256 * 3 - 2 * cnt;
        best = (ksum > best) ? ksum : best;
    }
    double conv = 0.1 * (double)best + (double)b[co];
    double v = ((sw[co] >= 0.0f) ? 0.1 : -0.1) * conv + (double)sb[co];
    a6[idx] = (v >= 0.0) ? (int8_t)1 : (int8_t)-1;
}

// FC1: a6[128][32] int8 @ sign(fw1[512][32]) -> affine -> sign -> packed h[128][8]
__global__ void fc1_kernel(const int8_t* __restrict__ a,
                           const float* __restrict__ fw1,
                           const float* __restrict__ fsw,
                           const float* __restrict__ fsb,
                           u64* __restrict__ hpk)
{
    int idx = blockIdx.x * blockDim.x + threadIdx.x;
    if (idx >= 128 * 512) return;
    int o = idx % 512;
    int n = idx / 512;
    int k = 0;
    #pragma unroll
    for (int i = 0; i < 32; ++i) {
        int av = (int)a[n * 32 + i];
        k += (fw1[o * 32 + i] >= 0.0f) ? av : -av;
    }
    double v = ((fsw[o] >= 0.0f) ? 0.1 : -0.1) * (0.1 * (double)k) + (double)fsb[o];
    u64 word = __ballot(v >= 0.0);
    if ((threadIdx.x & 63) == 0) hpk[idx >> 6] = word;
}

// FC2: h[128][8]u64 xnor fpk2[1000][8] -> affine -> out f32 [128][1000]
__global__ void fc2_kernel(const u64* __restrict__ hpk,
                           const u64* __restrict__ fpk2,
                           const float* __restrict__ fsw,
                           const float* __restrict__ fsb,
                           float* __restrict__ out)
{
    int idx = blockIdx.x * blockDim.x + threadIdx.x;
    if (idx >= 128 * 1000) return;
    int o = idx % 1000;
    int n = idx / 1000;
    int cnt = 0;
    #pragma unroll
    for (int w = 0; w < 8; ++w)
        cnt += __popcll(hpk[n * 8 + w] ^ fpk2[o * 8 + w]);
    int k = 512 - 2 * cnt;
    double v = ((fsw[o] >= 0.0f) ? 0.1 : -0.1) * (0.1 * (double)k) + (double)fsb[o];
    out[idx] = (float)v;
}

extern "C" void kernel_launch(void* const* d_in, const int* in_sizes, int n_in,
                              void* d_out, int out_size, void* d_ws, size_t ws_size,
                              hipStream_t stream) {
    const float* x = (const float*)d_in[0];
    const float *w[6], *b[6], *sw[6], *sb[6];
    for (int i = 0; i < 6; ++i) {
        w[i]  = (const float*)d_in[1 + 4 * i];
        b[i]  = (const float*)d_in[2 + 4 * i];
        sw[i] = (const float*)d_in[3 + 4 * i];
        sb[i] = (const float*)d_in[4 + 4 * i];
    }
    const float* fw1  = (const float*)d_in[25];
    const float* fsw1 = (const float*)d_in[26];
    const float* fsb1 = (const float*)d_in[27];
    const float* fw2  = (const float*)d_in[28];
    const float* fsw2 = (const float*)d_in[29];
    const float* fsb2 = (const float*)d_in[30];
    float* out = (float*)d_out;
    (void)in_sizes; (void)n_in; (void)out_size; (void)ws_size;

    char* wsbase = (char*)d_ws;
    size_t off = 0;
    auto alloc = [&](size_t bytes) -> char* {
        char* p = wsbase + off;
        off = (off + bytes + 255) & ~(size_t)255;
        return p;
    };
    u64* wpk2 = (u64*)alloc((size_t)13 * 256 * 4 * 8);
    u64* wpk3 = (u64*)alloc((size_t)7 * 256 * 4 * 8);
    u64* wpk4 = (u64*)alloc((size_t)5 * 256 * 4 * 8);
    u64* wpk5 = (u64*)alloc((size_t)5 * 256 * 4 * 8);
    u64* wpk6 = (u64*)alloc((size_t)3 * 8 * 4 * 8);
    u64* fpk2 = (u64*)alloc((size_t)1000 * 8 * 8);
    float* sgnf = (float*)alloc((size_t)69 * 256 * 4);
    u16* uflag16 = (u16*)alloc((size_t)128 * 482 * 16 * 2);
    u64* a1   = (u64*)alloc((size_t)128 * 482 * 4 * 8);
    u64* a2   = (u64*)alloc((size_t)128 * 149 * 4 * 8);
    u64* a3   = (u64*)alloc((size_t)128 * 46 * 4 * 8);
    u64* a4   = (u64*)alloc((size_t)128 * 42 * 4 * 8);
    u64* a5   = (u64*)alloc((size_t)128 * 13 * 4 * 8);
    int8_t* a6 = (int8_t*)alloc((size_t)128 * 32);
    u64* hpk  = (u64*)alloc((size_t)128 * 8 * 8);
    u16* opk16 = (u16*)a1;  // u16 word (co/16) aliases u64 word (co/64) bits

    const int BLK = 256;
    auto blocksForWaves = [](int nwaves) { return dim3((unsigned)((nwaves * 64 + 255) / 256)); };
    auto blocksForThreads = [](int n) { return dim3((unsigned)((n + 255) / 256)); };

    // merged weight packing (fc jobs expressed as K=1)
    {
        PackJobs P;
        int base = 0;
        auto setJob = [&](int i, const float* src, u64* dst, int Cout, int CIN, int K) {
            P.j[i] = {src, dst, Cout, CIN, K, base};
            base += K * Cout * (CIN >> 6);
        };
        setJob(0, w[1], wpk2, 256, 256, 13);
        setJob(1, w[2], wpk3, 256, 256, 7);
        setJob(2, w[3], wpk4, 256, 256, 5);
        setJob(3, w[4], wpk5, 256, 256, 5);
        setJob(4, w[5], wpk6, 8, 256, 3);
        setJob(5, fw2, fpk2, 1000, 512, 1);
        P.totalWaves = base;
        pack_all_kernel<<<blocksForWaves(base), BLK, 0, stream>>>(P);
    }
    pack_sgn1_kernel<<<blocksForThreads(69 * 256), BLK, 0, stream>>>(w[0], sgnf);

    // layer 1: fast f32 pass + f64 fixup of near-zero outputs
    conv1_pass1_kernel<<<dim3(128, 10, 16), BLK, 0, stream>>>(
        x, sgnf, b[0], sw[0], sb[0], opk16, uflag16);
    conv1_fixup_kernel<<<blocksForThreads(128 * 482 * 16), BLK, 0, stream>>>(
        x, w[0], b[0], sw[0], sb[0], uflag16, opk16);

    // layer 2: K=13 dil=3 pool(3,1): Lin=482 Lconv=446 Lout=149
    {
        const int NLPG = (149 + 3) / 4;
        int nw = 128 * NLPG * 4;
        bconv_bit_kernel<13, 3, 3, 1, 4, 4><<<blocksForWaves(nw), BLK, 0, stream>>>(
            a1, wpk2, b[1], sw[1], sb[1], a2, 256, 482, 446, 149, NLPG, nw);
    }
    // layer 3: K=7 dil=2 pool(3,1): Lin=149 Lconv=137 Lout=46
    {
        const int NLPG = (46 + 3) / 4;
        int nw = 128 * NLPG * 4;
        bconv_bit_kernel<7, 2, 3, 1, 4, 4><<<blocksForWaves(nw), BLK, 0, stream>>>(
            a2, wpk3, b[2], sw[2], sb[2], a3, 256, 149, 137, 46, NLPG, nw);
    }
    // layer 4: K=5 dil=1 no pool: Lin=46 Lconv=42 Lout=42
    {
        const int NLPG = (42 + 3) / 4;
        int nw = 128 * NLPG * 4;
        bconv_bit_kernel<5, 1, 1, 0, 4, 4><<<blocksForWaves(nw), BLK, 0, stream>>>(
            a3, wpk4, b[3], sw[3], sb[3], a4, 256, 46, 42, 42, NLPG, nw);
    }
    // layer 5: K=5 dil=1 pool(3,1): Lin=42 Lconv=38 Lout=13
    {
        const int NLPG = (13 + 3) / 4;
        int nw = 128 * NLPG * 4;
        bconv_bit_kernel<5, 1, 3, 1, 4, 4><<<blocksForWaves(nw), BLK, 0, stream>>>(
            a4, wpk5, b[4], sw[4], sb[4], a5, 256, 42, 38, 13, NLPG, nw);
    }
    // layer 6: Cout=8 K=3 pool(3,1): Lin=13 Lconv=11 Lout=4
    bconv6_kernel<<<blocksForThreads(128 * 8 * 4), BLK, 0, stream>>>(a5, wpk6, b[5], sw[5], sb[5], a6);

    // fc1 + fc2
    fc1_kernel<<<blocksForThreads(128 * 512), BLK, 0, stream>>>(a6, fw1, fsw1, fsb1, hpk);
    fc2_kernel<<<blocksForThreads(128 * 1000), BLK, 0, stream>>>(hpk, fpk2, fsw2, fsb2, out);
}